// Round 12
// baseline (276.707 us; speedup 1.0000x reference)
//
#include <hip/hip_runtime.h>
#include <hip/hip_bf16.h>

typedef unsigned short u16;
typedef unsigned int   u32;
typedef __bf16 bf16x8 __attribute__((ext_vector_type(8)));
typedef __bf16 bf16x4 __attribute__((ext_vector_type(4)));
typedef short  s16x4  __attribute__((ext_vector_type(4)));
typedef float  f32x4  __attribute__((ext_vector_type(4)));
typedef u16    u16x8  __attribute__((ext_vector_type(8)));
typedef u16    u16x4  __attribute__((ext_vector_type(4)));
typedef u32    u32x2  __attribute__((ext_vector_type(2)));

#define MFMA16(a,b,c) __builtin_amdgcn_mfma_f32_16x16x32_bf16(a,b,c,0,0,0)
#define LOG2E 1.4426950408889634f

// K=16 MFMA for PV chaining: D-frag of QK^T == B-frag of 16x16x16 (k=quad*4+j)
__device__ __forceinline__ f32x4 mfma16k16(bf16x4 a, bf16x4 b, f32x4 c) {
#if __has_builtin(__builtin_amdgcn_mfma_f32_16x16x16bf16_1k)
    return __builtin_amdgcn_mfma_f32_16x16x16bf16_1k(
        __builtin_bit_cast(s16x4, a), __builtin_bit_cast(s16x4, b), c, 0, 0, 0);
#elif __has_builtin(__builtin_amdgcn_mfma_f32_16x16x16_bf16_1k)
    return __builtin_amdgcn_mfma_f32_16x16x16_bf16_1k(
        __builtin_bit_cast(s16x4, a), __builtin_bit_cast(s16x4, b), c, 0, 0, 0);
#else
    asm("v_mfma_f32_16x16x16_bf16 %0, %1, %2, %0" : "+v"(c) : "v"(a), "v"(b));
    return c;
#endif
}

__device__ __forceinline__ u16 f2b(float f) {
    u32 u = __builtin_bit_cast(u32, f);
    u32 r = (u + 0x7FFFu + ((u >> 16) & 1u)) >> 16;  // RNE
    return (u16)r;
}

typedef const __attribute__((address_space(1))) u32* gaddr_t;
typedef __attribute__((address_space(3))) u32*       laddr_t;
__device__ __forceinline__ void gl_lds16(const void* g, void* l) {
    __builtin_amdgcn_global_load_lds((gaddr_t)g, (laddr_t)l, 16, 0, 0);
}

// ---------------- fused prep: cast H (blocks 0..4095) | transpose W (4096..5119) | bias (5120..5375) ----------------
__global__ __launch_bounds__(256) void prep_kernel(
        const float* __restrict__ H, const float* __restrict__ wq,
        const float* __restrict__ wk, const float* __restrict__ wv,
        const float* __restrict__ wo, const float* __restrict__ rel_bias,
        u16* __restrict__ Hb, u16* __restrict__ Wt, u16* __restrict__ Wot,
        float* __restrict__ tab) {
    __shared__ u16 tile[64 * 72];
    int bi = blockIdx.x;
    int t = threadIdx.x;
    if (bi < 4096) {
        // cast hidden_states fp32 -> bf16
        int i = (bi * 256 + t) * 8;
        float4 a = *(const float4*)(H + i);
        float4 b = *(const float4*)(H + i + 4);
        u16x8 o = { f2b(a.x), f2b(a.y), f2b(a.z), f2b(a.w),
                    f2b(b.x), f2b(b.y), f2b(b.z), f2b(b.w) };
        *(u16x8*)(Hb + i) = o;
    } else if (bi < 5120) {
        // transpose+cast weights [K=1024][N=1024] -> bf16 [N][K]
        int g2 = bi - 4096;
        int g = g2 >> 8, rem = g2 & 255;
        int n0 = (rem >> 4) * 64, k0 = (rem & 15) * 64;
        const float* src = (g == 0) ? wq : (g == 1) ? wk : (g == 2) ? wv : wo;
        u16* dst = (g < 3) ? (Wt + g * 1048576) : Wot;
#pragma unroll
        for (int rr = 0; rr < 4; ++rr) {
            int idx = rr * 256 + t;
            int kr = idx >> 4, c = idx & 15;
            float4 v = *(const float4*)(src + (k0 + kr) * 1024 + n0 + c * 4);
            u16x4 o = { f2b(v.x), f2b(v.y), f2b(v.z), f2b(v.w) };
            *(u16x4*)&tile[kr * 72 + c * 4] = o;
        }
        __syncthreads();
#pragma unroll
        for (int rr = 0; rr < 2; ++rr) {
            int idx = rr * 256 + t;
            int n = idx >> 3, c = idx & 7;
            u16x8 o;
#pragma unroll
            for (int j = 0; j < 8; ++j) o[j] = tile[(c * 8 + j) * 72 + n];
            *(u16x8*)(dst + (n0 + n) * 1024 + k0 + c * 8) = o;
        }
    } else {
        // bias_tab[h][delta+2048] = rel_bias[bucket(delta)][h] * log2e
        int i = (bi - 5120) * 256 + t;    // 16*4096
        int h = i >> 12;
        int idx = i & 4095;
        int delta = idx - 2048;            // k - q
        int bucket = (delta > 0) ? 16 : 0;
        int rp = delta < 0 ? -delta : delta;
        if (rp < 8) {
            bucket += rp;
        } else {
            // tt = floor(log2(rp/8)*2); crossings at 8*2^(n/2): n even = pow2
            // (exact in float), n odd irrational -> never integer rp. Safe.
            float lv = __log2f((float)rp) - 3.0f;
            int tt = (int)(lv * 2.0f);
            int b2 = 8 + tt;
            bucket += (b2 < 15) ? b2 : 15;
        }
        tab[h * 4096 + idx] = rel_bias[bucket * 16 + h] * LOG2E;
    }
}

// ---------------- 128x128 GEMM, BK=32, counted-vmcnt double-buffer (R10/R11) ----------------
// R12: coalesced epilogues. Old q/k path: 64 scalar u16 stores/thread (4 rows
// x 32B segments per wave + 64 addr calcs). Old MODE1: 64 scalar f32 stores.
// Now ALL outputs stage through the (post-loop free) LDS pool and store
// coalesced 16B chunks, like the proven V path:
//   q/k: [128][136] u16 staging -> u16x8 row stores.
//   MODE1: two-pass [64][136] f32 staging (wm==p waves write) -> float4.
// Pool = 34,816 B in both modes -> 4 blocks/CU unchanged.
template <int MODE>
__global__ __launch_bounds__(256) void gemm_bt(
        const u16* __restrict__ A, const u16* __restrict__ Bt, int K, int N,
        u16* __restrict__ q_out, u16* __restrict__ k_out, u16* __restrict__ v_out,
        float* __restrict__ f_out) {
    __shared__ char pool_raw[34816];
    // As[buf] at pool + buf*8192 ; Bs[buf] at pool + 16384 + buf*8192
    u16* vt_tile = (u16*)pool_raw;         // epilogue staging (after final barrier)
    int t = threadIdx.x;
    int lane = t & 63, w = t >> 6;
    int wm = w & 1, wn = w >> 1;
    int ln = lane & 15, quad = lane >> 4;
    // --- XCD-chunked decode: bid -> (bx, by) ---
    int bid = (int)blockIdx.x;
    int xcd = bid & 7;
    int r = bid >> 3;
    int by = r >> 3;          // n-panel index, 8 blocks per panel per XCD
    int bxl = r & 7;          // local m-panel within this XCD's 8-panel chunk
    int m0 = (xcd * 8 + bxl) * 128;
    int n0 = by * 128;
    const u16* Ab = A + m0 * K;
    const u16* Bb = Bt + n0 * K;
    f32x4 acc[4][4] = {};
    int nk = K >> 5;

    auto stage = [&](int kt, int buf) {
        int k0 = kt * 32;
        char* Ad = pool_raw + buf * 8192;
        char* Bd = pool_raw + 16384 + buf * 8192;
#pragma unroll
        for (int rr = 0; rr < 2; ++rr) {
            int idx = rr * 256 + t;
            int row = idx >> 2, c = (idx & 3) ^ (row & 3);
            gl_lds16(Ab + row * K + k0 + c * 8, Ad + idx * 16);
            gl_lds16(Bb + row * K + k0 + c * 8, Bd + idx * 16);
        }
    };
    auto compute = [&](int buf) {
        const u16* As = (const u16*)(pool_raw + buf * 8192);
        const u16* Bs = (const u16*)(pool_raw + 16384 + buf * 8192);
        bf16x8 af[4], bfr[4];
#pragma unroll
        for (int mb = 0; mb < 4; ++mb) {
            int row = wm * 64 + mb * 16 + ln;
            af[mb] = *(const bf16x8*)&As[row * 32 + ((quad ^ (row & 3)) << 3)];
        }
#pragma unroll
        for (int nb = 0; nb < 4; ++nb) {
            int row = wn * 64 + nb * 16 + ln;
            bfr[nb] = *(const bf16x8*)&Bs[row * 32 + ((quad ^ (row & 3)) << 3)];
        }
        __builtin_amdgcn_s_setprio(1);
#pragma unroll
        for (int mb = 0; mb < 4; ++mb)
#pragma unroll
            for (int nb = 0; nb < 4; ++nb)
                acc[mb][nb] = MFMA16(af[mb], bfr[nb], acc[mb][nb]);
        __builtin_amdgcn_s_setprio(0);
    };

    // ---- counted-vmcnt double-buffer pipeline (attn-proven protocol) ----
    stage(0, 0);
    for (int kt = 0; kt < nk - 1; ++kt) {
        stage(kt + 1, (kt + 1) & 1);                     // 4 loads/thread in flight
        asm volatile("s_waitcnt vmcnt(4)" ::: "memory"); // tile kt's loads done
        __builtin_amdgcn_sched_barrier(0);
        __builtin_amdgcn_s_barrier();                    // raw: no vmcnt drain
        compute(kt & 1);
        __builtin_amdgcn_s_barrier();                    // buf free for next stage
    }
    asm volatile("s_waitcnt vmcnt(0)" ::: "memory");
    __builtin_amdgcn_sched_barrier(0);
    __builtin_amdgcn_s_barrier();
    compute((nk - 1) & 1);

    // ---- epilogue: C/D layout col = lane&15, row = quad*4 + reg ----
    __syncthreads();   // all waves done reading As/Bs before pool overwrite
    if (MODE == 0 && n0 >= 2048) {
        // v-region: transpose via LDS, store Vt[bh][d][s]
#pragma unroll
        for (int mb = 0; mb < 4; ++mb)
#pragma unroll
            for (int nb = 0; nb < 4; ++nb)
#pragma unroll
                for (int r2 = 0; r2 < 4; ++r2) {
                    int np = wn * 64 + nb * 16 + ln;            // n - n0
                    int mp = wm * 64 + mb * 16 + quad * 4 + r2; // m - m0 (= s offset)
                    vt_tile[np * 136 + mp] = f2b(acc[mb][nb][r2]);
                }
        __syncthreads();
        int h0 = (n0 >> 6) & 15;
        int b = m0 >> 11;
        int s0 = m0 & 2047;                // s-base within the batch
#pragma unroll
        for (int j = 0; j < 8; ++j) {
            int e = j * 256 + t;
            int d_all = e >> 4;            // n' in [0,128): h_off*64 + d
            int sc = e & 15;
            int hh = h0 + (d_all >> 6);
            int d = d_all & 63;
            u16x8 val = *(const u16x8*)&vt_tile[d_all * 136 + sc * 8];
            *(u16x8*)(v_out + (b * 16 + hh) * 131072 + d * 2048 + s0 + sc * 8) = val;
        }
    } else if (MODE == 0) {
        // q/k: stage [m'][n'] (136-stride), then coalesced u16x8 row stores
        u16* st = (u16*)pool_raw;
        u16* dst = (n0 >= 1024) ? k_out : q_out;
        float scale = (n0 >= 1024) ? 1.0f : LOG2E;
#pragma unroll
        for (int mb = 0; mb < 4; ++mb)
#pragma unroll
            for (int nb = 0; nb < 4; ++nb)
#pragma unroll
                for (int r2 = 0; r2 < 4; ++r2) {
                    int mp = wm * 64 + mb * 16 + quad * 4 + r2;
                    int np = wn * 64 + nb * 16 + ln;
                    st[mp * 136 + np] = f2b(acc[mb][nb][r2] * scale);
                }
        __syncthreads();
        int h0 = (n0 >> 6) & 15;
        int bb = m0 >> 11;
        int s0 = m0 & 2047;
#pragma unroll
        for (int j = 0; j < 8; ++j) {
            int e = j * 256 + t;           // 2048 = 128 rows x 16 chunks
            int mp = e >> 4, c = e & 15;
            u16x8 val = *(const u16x8*)&st[mp * 136 + c * 8];
            int h = h0 + (c >> 3);
            int d = (c & 7) * 8;
            *(u16x8*)(dst + (((bb << 4) + h) * 2048 + s0 + mp) * 64 + d) = val;
        }
    } else {
        // MODE 1: two-pass f32 staging [64][136] -> coalesced float4 stores
        float* stf = (float*)pool_raw;
#pragma unroll
        for (int p = 0; p < 2; ++p) {
            if (wm == p) {
#pragma unroll
                for (int mb = 0; mb < 4; ++mb)
#pragma unroll
                    for (int nb = 0; nb < 4; ++nb)
#pragma unroll
                        for (int r2 = 0; r2 < 4; ++r2) {
                            int mp = mb * 16 + quad * 4 + r2;   // within 64
                            int np = wn * 64 + nb * 16 + ln;
                            stf[mp * 136 + np] = acc[mb][nb][r2];
                        }
            }
            __syncthreads();
#pragma unroll
            for (int j = 0; j < 8; ++j) {
                int e = j * 256 + t;       // 2048 float4 = 64 rows x 32 chunks
                int mp = e >> 5, c = e & 31;
                float4 val = *(const float4*)&stf[mp * 136 + c * 4];
                *(float4*)(f_out + (m0 + p * 64 + mp) * N + n0 + c * 4) = val;
            }
            if (p == 0) __syncthreads();
        }
    }
}

// ---------------- Flash attention: 128-q blocks, S^T, exp2-domain (R8-proven) ----------------
__global__ __launch_bounds__(256, 4) void attn_kernel(
        const u16* __restrict__ Qb, const u16* __restrict__ Kb,
        const u16* __restrict__ Vt, const float* __restrict__ bias_tab,
        u16* __restrict__ ctx) {
    __shared__ u16 Ks[2][64 * 64];   // [key][d], swizzled (chunk ^ (key&7))
    __shared__ u16 Vs[2][64 * 64];   // [d][key], swizzled (chunk ^ (d&7))
    __shared__ float sb[384];        // diagonal bias window (already *log2e)
    int t = threadIdx.x;
    int lane = t & 63, w = t >> 6;
    int ln = lane & 15, quad = lane >> 4;
    int bid = blockIdx.x;
    int bh = (bid & 7) * 8 + (bid >> 7);   // XCD (bid%8) owns bh in [8x, 8x+8)
    int qtile = (bid >> 3) & 15;
    int h = bh & 15, b = bh >> 4;
    int q0 = qtile * 128;

    float chi = bias_tab[h * 4096 + 2048 + 1500];   // delta >= 128 bucket
    float clo = bias_tab[h * 4096 + 2048 - 1500];   // delta <= -128 bucket

    // sb[i] = tab[h][1857 + i]  (deltas -191..+192, translation-invariant)
    const float* tb = bias_tab + h * 4096 + 1857;
    for (int i = t; i < 384; i += 256) sb[i] = tb[i];

    // Q fragments for 2 q-groups (B-operand: n = ln, k = quad*8+j)
    const u16* qbase = Qb + (bh * 2048 + q0 + w * 16 + ln) * 64 + quad * 8;
    bf16x8 qf[2][2];
    qf[0][0] = *(const bf16x8*)(qbase);
    qf[0][1] = *(const bf16x8*)(qbase + 32);
    qf[1][0] = *(const bf16x8*)(qbase + 64 * 64);
    qf[1][1] = *(const bf16x8*)(qbase + 64 * 64 + 32);

    const u16* Kbase = Kb + bh * 2048 * 64;
    const u16* Vbase = Vt + bh * 64 * 2048;

    f32x4 oacc[2][4] = {};
    float l0 = 0.0f, l1 = 0.0f;
    int cb2_base = 191 - w * 16 + quad * 4 - ln;

    // stage one 64-key tile: 4 VMEM ops/lane
    auto stage = [&](int kb, int bufidx) {
#pragma unroll
        for (int it = 0; it < 2; ++it) {
            int idx = it * 256 + t;
            int row = idx >> 3, c = (idx & 7) ^ (row & 7);
            gl_lds16(Kbase + (kb + row) * 64 + c * 8,
                     ((char*)&Ks[bufidx][0]) + idx * 16);
            gl_lds16(Vbase + row * 2048 + kb + c * 8,
                     ((char*)&Vs[bufidx][0]) + idx * 16);
        }
    };

    auto compute = [&](int kb0, const u16* Kc, const u16* Vc) {
        // ---- S^T = K·Q^T, bias as C-init; K-frags shared across both q-groups ----
        f32x4 sacc[2][4];
        int diffs[2] = {kb0 - q0, kb0 - q0 - 64};
        __builtin_amdgcn_s_setprio(1);
#pragma unroll
        for (int nb = 0; nb < 4; ++nb) {
            int key = nb * 16 + ln;
            int sw = key & 7;
            bf16x8 kf0 = *(const bf16x8*)&Kc[key * 64 + ((quad ^ sw) << 3)];
            bf16x8 kf1 = *(const bf16x8*)&Kc[key * 64 + (((quad ^ 4) ^ sw) << 3)];
#pragma unroll
            for (int g = 0; g < 2; ++g) {
                int diff = diffs[g];
                f32x4 ci;
                if (diff >= 192 || diff <= -192) {
                    float c0 = (diff > 0) ? chi : clo;
                    ci = {c0, c0, c0, c0};
                } else {
                    const float* bp = &sb[diff + cb2_base + nb * 16];
                    ci = {bp[0], bp[1], bp[2], bp[3]};
                }
                f32x4 scc = MFMA16(kf0, qf[g][0], ci);
                sacc[g][nb] = MFMA16(kf1, qf[g][1], scc);
            }
        }
        __builtin_amdgcn_s_setprio(0);

        // ---- p = exp2(s); accumulate l; pack to bf16 B-frags in-register ----
        bf16x4 pb[2][4];
#pragma unroll
        for (int g = 0; g < 2; ++g) {
            float s0 = 0.f, s1 = 0.f, s2 = 0.f, s3 = 0.f;
#pragma unroll
            for (int nb = 0; nb < 4; ++nb) {
                float e0 = __builtin_amdgcn_exp2f(sacc[g][nb][0]);
                float e1 = __builtin_amdgcn_exp2f(sacc[g][nb][1]);
                float e2 = __builtin_amdgcn_exp2f(sacc[g][nb][2]);
                float e3 = __builtin_amdgcn_exp2f(sacc[g][nb][3]);
                s0 += e0; s1 += e1; s2 += e2; s3 += e3;
                u32 lo, hi;
                asm("v_cvt_pk_bf16_f32 %0, %1, %2" : "=v"(lo) : "v"(e0), "v"(e1));
                asm("v_cvt_pk_bf16_f32 %0, %1, %2" : "=v"(hi) : "v"(e2), "v"(e3));
                u32x2 uv = {lo, hi};
                pb[g][nb] = __builtin_bit_cast(bf16x4, uv);
            }
            if (g == 0) l0 += (s0 + s1) + (s2 + s3);
            else        l1 += (s0 + s1) + (s2 + s3);
        }

        // ---- O^T += V^T · P : A = V^T (row=d=ln, k=key=quad*4+j), B = pb ----
        __builtin_amdgcn_s_setprio(1);
#pragma unroll
        for (int kc = 0; kc < 4; ++kc) {
            bf16x4 vA[4];
#pragma unroll
            for (int nd = 0; nd < 4; ++nd) {
                int d = nd * 16 + ln;
                int ch = (kc * 2 + (quad >> 1)) ^ (d & 7);
                vA[nd] = *(const bf16x4*)&Vc[d * 64 + (ch << 3) + ((quad & 1) << 2)];
            }
#pragma unroll
            for (int nd = 0; nd < 4; ++nd)
#pragma unroll
                for (int g = 0; g < 2; ++g)
                    oacc[g][nd] = mfma16k16(vA[nd], pb[g][kc], oacc[g][nd]);
        }
        __builtin_amdgcn_s_setprio(0);
    };

    // ---- counted-vmcnt double-buffer pipeline ----
    stage(0, 0);
    asm volatile("s_waitcnt lgkmcnt(0)" ::: "memory");  // sb ds_writes drained pre-barrier
    for (int kt = 0; kt < 31; ++kt) {
        int cur = kt & 1;
        stage((kt + 1) * 64, cur ^ 1);                   // 4 loads/lane in flight
        asm volatile("s_waitcnt vmcnt(4)" ::: "memory"); // tile kt's loads done
        __builtin_amdgcn_sched_barrier(0);
        __builtin_amdgcn_s_barrier();                    // raw: no vmcnt drain
        compute(kt * 64, &Ks[cur][0], &Vs[cur][0]);
        __builtin_amdgcn_s_barrier();                    // buf cur free for next stage
    }
    asm volatile("s_waitcnt vmcnt(0)" ::: "memory");
    __builtin_amdgcn_sched_barrier(0);
    __builtin_amdgcn_s_barrier();
    compute(31 * 64, &Ks[1][0], &Vs[1][0]);

    // ---- epilogue: O^T lane holds q=ln -> linv is lane-local, no shuffles ----
    l0 += __shfl_xor(l0, 16); l0 += __shfl_xor(l0, 32);
    l1 += __shfl_xor(l1, 16); l1 += __shfl_xor(l1, 32);
    float linv[2] = {1.0f / l0, 1.0f / l1};
#pragma unroll
    for (int g = 0; g < 2; ++g) {
        int q = q0 + g * 64 + w * 16 + ln;
        u16* cp = ctx + (b * 2048 + q) * 1024 + h * 64 + quad * 4;
#pragma unroll
        for (int nd = 0; nd < 4; ++nd) {
            u16x4 o = { f2b(oacc[g][nd][0] * linv[g]), f2b(oacc[g][nd][1] * linv[g]),
                        f2b(oacc[g][nd][2] * linv[g]), f2b(oacc[g][nd][3] * linv[g]) };
            *(u16x4*)(cp + nd * 16) = o;
        }
    }
}

// ---------------- launch ----------------
extern "C" void kernel_launch(void* const* d_in, const int* in_sizes, int n_in,
                              void* d_out, int out_size, void* d_ws, size_t ws_size,
                              hipStream_t stream) {
    const float* H   = (const float*)d_in[0];
    const float* wq  = (const float*)d_in[1];
    const float* wk  = (const float*)d_in[2];
    const float* wv  = (const float*)d_in[3];
    const float* wo  = (const float*)d_in[4];
    const float* rel = (const float*)d_in[5];
    float* out = (float*)d_out;

    char* ws = (char*)d_ws;
    u16* Hb    = (u16*)(ws);                 // 16.78 MB; reused as ctx after gemm
    u16* Wt    = (u16*)(ws + 16777216);      // 6.29 MB (wq|wk|wv transposed)
    u16* Wot   = (u16*)(ws + 23068672);      // 2.10 MB
    u16* Qb    = (u16*)(ws + 25165824);      // 16.78 MB
    u16* Kb    = (u16*)(ws + 41943040);      // 16.78 MB
    u16* Vt    = (u16*)(ws + 58720256);      // 16.78 MB, [bh][d][s]
    float* bias_tab = (float*)(ws + 75497472); // 0.26 MB
    u16* ctx = Hb;

    prep_kernel<<<5376, 256, 0, stream>>>(H, wq, wk, wv, wo, rel, Hb, Wt, Wot, bias_tab);
    gemm_bt<0><<<1536, 256, 0, stream>>>(Hb, Wt, 1024, 3072, Qb, Kb, Vt, nullptr);
    attn_kernel<<<1024, 256, 0, stream>>>(Qb, Kb, Vt, bias_tab, ctx);
    gemm_bt<1><<<512, 256, 0, stream>>>(ctx, Wot, 1024, 1024, nullptr, nullptr, nullptr, out);
}

// Round 13
// 266.370 us; speedup vs baseline: 1.0388x; 1.0388x over previous
//
#include <hip/hip_runtime.h>
#include <hip/hip_bf16.h>

typedef unsigned short u16;
typedef unsigned int   u32;
typedef __bf16 bf16x8 __attribute__((ext_vector_type(8)));
typedef __bf16 bf16x4 __attribute__((ext_vector_type(4)));
typedef short  s16x4  __attribute__((ext_vector_type(4)));
typedef float  f32x4  __attribute__((ext_vector_type(4)));
typedef u16    u16x8  __attribute__((ext_vector_type(8)));
typedef u16    u16x4  __attribute__((ext_vector_type(4)));
typedef u32    u32x2  __attribute__((ext_vector_type(2)));

#define MFMA16(a,b,c) __builtin_amdgcn_mfma_f32_16x16x32_bf16(a,b,c,0,0,0)
#define LOG2E 1.4426950408889634f

// K=16 MFMA for PV chaining: D-frag of QK^T == B-frag of 16x16x16 (k=quad*4+j)
__device__ __forceinline__ f32x4 mfma16k16(bf16x4 a, bf16x4 b, f32x4 c) {
#if __has_builtin(__builtin_amdgcn_mfma_f32_16x16x16bf16_1k)
    return __builtin_amdgcn_mfma_f32_16x16x16bf16_1k(
        __builtin_bit_cast(s16x4, a), __builtin_bit_cast(s16x4, b), c, 0, 0, 0);
#elif __has_builtin(__builtin_amdgcn_mfma_f32_16x16x16_bf16_1k)
    return __builtin_amdgcn_mfma_f32_16x16x16_bf16_1k(
        __builtin_bit_cast(s16x4, a), __builtin_bit_cast(s16x4, b), c, 0, 0, 0);
#else
    asm("v_mfma_f32_16x16x16_bf16 %0, %1, %2, %0" : "+v"(c) : "v"(a), "v"(b));
    return c;
#endif
}

__device__ __forceinline__ u16 f2b(float f) {
    u32 u = __builtin_bit_cast(u32, f);
    u32 r = (u + 0x7FFFu + ((u >> 16) & 1u)) >> 16;  // RNE
    return (u16)r;
}

typedef const __attribute__((address_space(1))) u32* gaddr_t;
typedef __attribute__((address_space(3))) u32*       laddr_t;
__device__ __forceinline__ void gl_lds16(const void* g, void* l) {
    __builtin_amdgcn_global_load_lds((gaddr_t)g, (laddr_t)l, 16, 0, 0);
}

// ---------------- fused prep: cast H (blocks 0..4095) | transpose W (4096..5119) | bias (5120..5375) ----------------
__global__ __launch_bounds__(256) void prep_kernel(
        const float* __restrict__ H, const float* __restrict__ wq,
        const float* __restrict__ wk, const float* __restrict__ wv,
        const float* __restrict__ wo, const float* __restrict__ rel_bias,
        u16* __restrict__ Hb, u16* __restrict__ Wt, u16* __restrict__ Wot,
        float* __restrict__ tab) {
    __shared__ u16 tile[64 * 72];
    int bi = blockIdx.x;
    int t = threadIdx.x;
    if (bi < 4096) {
        // cast hidden_states fp32 -> bf16
        int i = (bi * 256 + t) * 8;
        float4 a = *(const float4*)(H + i);
        float4 b = *(const float4*)(H + i + 4);
        u16x8 o = { f2b(a.x), f2b(a.y), f2b(a.z), f2b(a.w),
                    f2b(b.x), f2b(b.y), f2b(b.z), f2b(b.w) };
        *(u16x8*)(Hb + i) = o;
    } else if (bi < 5120) {
        // transpose+cast weights [K=1024][N=1024] -> bf16 [N][K]
        int g2 = bi - 4096;
        int g = g2 >> 8, rem = g2 & 255;
        int n0 = (rem >> 4) * 64, k0 = (rem & 15) * 64;
        const float* src = (g == 0) ? wq : (g == 1) ? wk : (g == 2) ? wv : wo;
        u16* dst = (g < 3) ? (Wt + g * 1048576) : Wot;
#pragma unroll
        for (int rr = 0; rr < 4; ++rr) {
            int idx = rr * 256 + t;
            int kr = idx >> 4, c = idx & 15;
            float4 v = *(const float4*)(src + (k0 + kr) * 1024 + n0 + c * 4);
            u16x4 o = { f2b(v.x), f2b(v.y), f2b(v.z), f2b(v.w) };
            *(u16x4*)&tile[kr * 72 + c * 4] = o;
        }
        __syncthreads();
#pragma unroll
        for (int rr = 0; rr < 2; ++rr) {
            int idx = rr * 256 + t;
            int n = idx >> 3, c = idx & 7;
            u16x8 o;
#pragma unroll
            for (int j = 0; j < 8; ++j) o[j] = tile[(c * 8 + j) * 72 + n];
            *(u16x8*)(dst + (n0 + n) * 1024 + k0 + c * 8) = o;
        }
    } else {
        // bias_tab[h][delta+2048] = rel_bias[bucket(delta)][h] * log2e
        int i = (bi - 5120) * 256 + t;    // 16*4096
        int h = i >> 12;
        int idx = i & 4095;
        int delta = idx - 2048;            // k - q
        int bucket = (delta > 0) ? 16 : 0;
        int rp = delta < 0 ? -delta : delta;
        if (rp < 8) {
            bucket += rp;
        } else {
            // tt = floor(log2(rp/8)*2); crossings at 8*2^(n/2): n even = pow2
            // (exact in float), n odd irrational -> never integer rp. Safe.
            float lv = __log2f((float)rp) - 3.0f;
            int tt = (int)(lv * 2.0f);
            int b2 = 8 + tt;
            bucket += (b2 < 15) ? b2 : 15;
        }
        tab[h * 4096 + idx] = rel_bias[bucket * 16 + h] * LOG2E;
    }
}

// ---------------- 128x128 GEMM, BK=32, counted-vmcnt double-buffer (R11-proven) ----------------
// R13: reverted to R11 epilogues (R12 LDS-staged stores were +4.5us).
// stage(t+1)->vmcnt(4)->raw barrier->compute(t)->raw barrier; XCD-chunked
// remap; pool 34.8KB -> 4 blocks/CU. MODE 0: qkv out; MODE 1: fp32 out.
template <int MODE>
__global__ __launch_bounds__(256) void gemm_bt(
        const u16* __restrict__ A, const u16* __restrict__ Bt, int K, int N,
        u16* __restrict__ q_out, u16* __restrict__ k_out, u16* __restrict__ v_out,
        float* __restrict__ f_out) {
    __shared__ char pool_raw[MODE == 0 ? 128 * 136 * 2 : 32768];
    // As[buf] at pool + buf*8192 ; Bs[buf] at pool + 16384 + buf*8192
    u16* vt_tile = (u16*)pool_raw;         // MODE0 epilogue reuse (after barrier)
    int t = threadIdx.x;
    int lane = t & 63, w = t >> 6;
    int wm = w & 1, wn = w >> 1;
    int ln = lane & 15, quad = lane >> 4;
    // --- XCD-chunked decode: bid -> (bx, by) ---
    int bid = (int)blockIdx.x;
    int xcd = bid & 7;
    int r = bid >> 3;
    int by = r >> 3;          // n-panel index, 8 blocks per panel per XCD
    int bxl = r & 7;          // local m-panel within this XCD's 8-panel chunk
    int m0 = (xcd * 8 + bxl) * 128;
    int n0 = by * 128;
    const u16* Ab = A + m0 * K;
    const u16* Bb = Bt + n0 * K;
    f32x4 acc[4][4] = {};
    int nk = K >> 5;

    auto stage = [&](int kt, int buf) {
        int k0 = kt * 32;
        char* Ad = pool_raw + buf * 8192;
        char* Bd = pool_raw + 16384 + buf * 8192;
#pragma unroll
        for (int rr = 0; rr < 2; ++rr) {
            int idx = rr * 256 + t;
            int row = idx >> 2, c = (idx & 3) ^ (row & 3);
            gl_lds16(Ab + row * K + k0 + c * 8, Ad + idx * 16);
            gl_lds16(Bb + row * K + k0 + c * 8, Bd + idx * 16);
        }
    };
    auto compute = [&](int buf) {
        const u16* As = (const u16*)(pool_raw + buf * 8192);
        const u16* Bs = (const u16*)(pool_raw + 16384 + buf * 8192);
        bf16x8 af[4], bfr[4];
#pragma unroll
        for (int mb = 0; mb < 4; ++mb) {
            int row = wm * 64 + mb * 16 + ln;
            af[mb] = *(const bf16x8*)&As[row * 32 + ((quad ^ (row & 3)) << 3)];
        }
#pragma unroll
        for (int nb = 0; nb < 4; ++nb) {
            int row = wn * 64 + nb * 16 + ln;
            bfr[nb] = *(const bf16x8*)&Bs[row * 32 + ((quad ^ (row & 3)) << 3)];
        }
        __builtin_amdgcn_s_setprio(1);
#pragma unroll
        for (int mb = 0; mb < 4; ++mb)
#pragma unroll
            for (int nb = 0; nb < 4; ++nb)
                acc[mb][nb] = MFMA16(af[mb], bfr[nb], acc[mb][nb]);
        __builtin_amdgcn_s_setprio(0);
    };

    // ---- counted-vmcnt double-buffer pipeline (attn-proven protocol) ----
    stage(0, 0);
    for (int kt = 0; kt < nk - 1; ++kt) {
        stage(kt + 1, (kt + 1) & 1);                     // 4 loads/thread in flight
        asm volatile("s_waitcnt vmcnt(4)" ::: "memory"); // tile kt's loads done
        __builtin_amdgcn_sched_barrier(0);
        __builtin_amdgcn_s_barrier();                    // raw: no vmcnt drain
        compute(kt & 1);
        __builtin_amdgcn_s_barrier();                    // buf free for next stage
    }
    asm volatile("s_waitcnt vmcnt(0)" ::: "memory");
    __builtin_amdgcn_sched_barrier(0);
    __builtin_amdgcn_s_barrier();
    compute((nk - 1) & 1);

    // epilogue — C/D layout: col = lane&15, row = quad*4 + reg
    if (MODE == 0 && n0 >= 2048) {
        // v-region: transpose via LDS (pool reused), store Vt[bh][d][s]
        __syncthreads();   // all waves done reading As/Bs before overwrite
#pragma unroll
        for (int mb = 0; mb < 4; ++mb)
#pragma unroll
            for (int nb = 0; nb < 4; ++nb)
#pragma unroll
                for (int r2 = 0; r2 < 4; ++r2) {
                    int np = wn * 64 + nb * 16 + ln;            // n - n0
                    int mp = wm * 64 + mb * 16 + quad * 4 + r2; // m - m0 (= s offset)
                    vt_tile[np * 136 + mp] = f2b(acc[mb][nb][r2]);
                }
        __syncthreads();
        int h0 = (n0 >> 6) & 15;
        int b = m0 >> 11;
        int s0 = m0 & 2047;                // s-base within the batch
#pragma unroll
        for (int j = 0; j < 8; ++j) {
            int e = j * 256 + t;
            int d_all = e >> 4;            // n' in [0,128): h_off*64 + d
            int sc = e & 15;
            int hh = h0 + (d_all >> 6);
            int d = d_all & 63;
            u16x8 val = *(const u16x8*)&vt_tile[d_all * 136 + sc * 8];
            *(u16x8*)(v_out + (b * 16 + hh) * 131072 + d * 2048 + s0 + sc * 8) = val;
        }
    } else {
#pragma unroll
        for (int mb = 0; mb < 4; ++mb)
#pragma unroll
            for (int nb = 0; nb < 4; ++nb)
#pragma unroll
                for (int r2 = 0; r2 < 4; ++r2) {
                    int m = m0 + wm * 64 + mb * 16 + quad * 4 + r2;
                    int n = n0 + wn * 64 + nb * 16 + ln;
                    float v = acc[mb][nb][r2];
                    if (MODE == 0) {
                        int which = n >> 10, h = (n >> 6) & 15, d = n & 63;
                        int b = m >> 11, s = m & 2047;
                        u16* dst = (which == 0) ? q_out : k_out;
                        float scale = (which == 0) ? LOG2E : 1.0f;
                        dst[(((b << 4) + h) * 2048 + s) * 64 + d] = f2b(v * scale);
                    } else {
                        f_out[m * N + n] = v;
                    }
                }
    }
}

// ---------------- Flash attention: 256-q blocks, S^T, exp2-domain (R13) ----------------
// R13: attn is LDS-throughput-bound (corrected model: exp2 floor ~14us/SIMD,
// MFMA ~8us, but K/V fragment reads = ~2.6GB LDS traffic ~ the 105us). QBLK
// 128->256: 4 q-groups/wave share K-fragments (loaded to regs once/tile) and
// V reads -> per-q LDS traffic halves (the same lever as R3's win). 512
// blocks = 2/CU (VGPR ~200, launch_bounds(256,2)). sb window bounds
// re-verified for per-g diff: i in [0,382]; saturation |delta|>=129.
__global__ __launch_bounds__(256, 2) void attn_kernel(
        const u16* __restrict__ Qb, const u16* __restrict__ Kb,
        const u16* __restrict__ Vt, const float* __restrict__ bias_tab,
        u16* __restrict__ ctx) {
    __shared__ u16 Ks[2][64 * 64];   // [key][d], swizzled (chunk ^ (key&7))
    __shared__ u16 Vs[2][64 * 64];   // [d][key], swizzled (chunk ^ (d&7))
    __shared__ float sb[384];        // diagonal bias window (already *log2e)
    int t = threadIdx.x;
    int lane = t & 63, w = t >> 6;
    int ln = lane & 15, quad = lane >> 4;
    int bid = blockIdx.x;
    int bh = (bid & 7) * 8 + (bid >> 6);   // XCD (bid%8) owns bh in [8x, 8x+8)
    int qtile = (bid >> 3) & 7;
    int h = bh & 15, b = bh >> 4;
    int q0 = qtile * 256;

    float chi = bias_tab[h * 4096 + 2048 + 1500];   // delta >= 128 bucket
    float clo = bias_tab[h * 4096 + 2048 - 1500];   // delta <= -128 bucket

    // sb[i] = tab[h][1857 + i]  (deltas -191..+192, translation-invariant)
    const float* tb = bias_tab + h * 4096 + 1857;
    for (int i = t; i < 384; i += 256) sb[i] = tb[i];

    // Q fragments for 4 q-groups (B-operand: n = ln, k = quad*8+j)
    const u16* qbase = Qb + (bh * 2048 + q0 + w * 16 + ln) * 64 + quad * 8;
    bf16x8 qf[4][2];
#pragma unroll
    for (int g = 0; g < 4; ++g) {
        qf[g][0] = *(const bf16x8*)(qbase + g * 4096);
        qf[g][1] = *(const bf16x8*)(qbase + g * 4096 + 32);
    }

    const u16* Kbase = Kb + bh * 2048 * 64;
    const u16* Vbase = Vt + bh * 64 * 2048;

    f32x4 oacc[4][4] = {};
    float lsum[4] = {0.f, 0.f, 0.f, 0.f};
    int cb2_base = 191 - w * 16 + quad * 4 - ln;

    // stage one 64-key tile: 4 VMEM ops/lane
    auto stage = [&](int kb, int bufidx) {
#pragma unroll
        for (int it = 0; it < 2; ++it) {
            int idx = it * 256 + t;
            int row = idx >> 3, c = (idx & 7) ^ (row & 7);
            gl_lds16(Kbase + (kb + row) * 64 + c * 8,
                     ((char*)&Ks[bufidx][0]) + idx * 16);
            gl_lds16(Vbase + row * 2048 + kb + c * 8,
                     ((char*)&Vs[bufidx][0]) + idx * 16);
        }
    };

    auto compute = [&](int kb0, const u16* Kc, const u16* Vc) {
        // ---- K fragments to registers once; shared by all 4 q-groups ----
        bf16x8 kf[4][2];
#pragma unroll
        for (int nb = 0; nb < 4; ++nb) {
            int key = nb * 16 + ln;
            int sw = key & 7;
            kf[nb][0] = *(const bf16x8*)&Kc[key * 64 + ((quad ^ sw) << 3)];
            kf[nb][1] = *(const bf16x8*)&Kc[key * 64 + (((quad ^ 4) ^ sw) << 3)];
        }
        // ---- per q-group: S^T = K·Q^T (bias C-init), exp2, pack ----
        bf16x4 pb[4][4];
#pragma unroll
        for (int g = 0; g < 4; ++g) {
            int diff = kb0 - q0 - g * 64;
            f32x4 sg[4];
            __builtin_amdgcn_s_setprio(1);
            if (diff >= 192 || diff <= -192) {
                float c0 = (diff > 0) ? chi : clo;
                f32x4 ci = {c0, c0, c0, c0};
#pragma unroll
                for (int nb = 0; nb < 4; ++nb) {
                    f32x4 scc = MFMA16(kf[nb][0], qf[g][0], ci);
                    sg[nb] = MFMA16(kf[nb][1], qf[g][1], scc);
                }
            } else {
                int cb = diff + cb2_base;
#pragma unroll
                for (int nb = 0; nb < 4; ++nb) {
                    const float* bp = &sb[cb + nb * 16];
                    f32x4 ci = {bp[0], bp[1], bp[2], bp[3]};
                    f32x4 scc = MFMA16(kf[nb][0], qf[g][0], ci);
                    sg[nb] = MFMA16(kf[nb][1], qf[g][1], scc);
                }
            }
            __builtin_amdgcn_s_setprio(0);
            float s0 = 0.f, s1 = 0.f, s2 = 0.f, s3 = 0.f;
#pragma unroll
            for (int nb = 0; nb < 4; ++nb) {
                float e0 = __builtin_amdgcn_exp2f(sg[nb][0]);
                float e1 = __builtin_amdgcn_exp2f(sg[nb][1]);
                float e2 = __builtin_amdgcn_exp2f(sg[nb][2]);
                float e3 = __builtin_amdgcn_exp2f(sg[nb][3]);
                s0 += e0; s1 += e1; s2 += e2; s3 += e3;
                u32 lo, hi;
                asm("v_cvt_pk_bf16_f32 %0, %1, %2" : "=v"(lo) : "v"(e0), "v"(e1));
                asm("v_cvt_pk_bf16_f32 %0, %1, %2" : "=v"(hi) : "v"(e2), "v"(e3));
                u32x2 uv = {lo, hi};
                pb[g][nb] = __builtin_bit_cast(bf16x4, uv);
            }
            lsum[g] += (s0 + s1) + (s2 + s3);
        }

        // ---- O^T += V^T · P : A = V^T (row=d=ln, k=key=quad*4+j), B = pb ----
        __builtin_amdgcn_s_setprio(1);
#pragma unroll
        for (int kc = 0; kc < 4; ++kc) {
            bf16x4 vA[4];
#pragma unroll
            for (int nd = 0; nd < 4; ++nd) {
                int d = nd * 16 + ln;
                int ch = (kc * 2 + (quad >> 1)) ^ (d & 7);
                vA[nd] = *(const bf16x4*)&Vc[d * 64 + (ch << 3) + ((quad & 1) << 2)];
            }
#pragma unroll
            for (int nd = 0; nd < 4; ++nd)
#pragma unroll
                for (int g = 0; g < 4; ++g)
                    oacc[g][nd] = mfma16k16(vA[nd], pb[g][kc], oacc[g][nd]);
        }
        __builtin_amdgcn_s_setprio(0);
    };

    // ---- counted-vmcnt double-buffer pipeline ----
    stage(0, 0);
    asm volatile("s_waitcnt lgkmcnt(0)" ::: "memory");  // sb ds_writes drained pre-barrier
    for (int kt = 0; kt < 31; ++kt) {
        int cur = kt & 1;
        stage((kt + 1) * 64, cur ^ 1);                   // 4 loads/lane in flight
        asm volatile("s_waitcnt vmcnt(4)" ::: "memory"); // tile kt's loads done
        __builtin_amdgcn_sched_barrier(0);
        __builtin_amdgcn_s_barrier();                    // raw: no vmcnt drain
        compute(kt * 64, &Ks[cur][0], &Vs[cur][0]);
        __builtin_amdgcn_s_barrier();                    // buf cur free for next stage
    }
    asm volatile("s_waitcnt vmcnt(0)" ::: "memory");
    __builtin_amdgcn_sched_barrier(0);
    __builtin_amdgcn_s_barrier();
    compute(31 * 64, &Ks[1][0], &Vs[1][0]);

    // ---- epilogue: O^T lane holds q=ln -> linv is lane-local, no shuffles ----
#pragma unroll
    for (int g = 0; g < 4; ++g) {
        lsum[g] += __shfl_xor(lsum[g], 16);
        lsum[g] += __shfl_xor(lsum[g], 32);
    }
#pragma unroll
    for (int g = 0; g < 4; ++g) {
        float linv = 1.0f / lsum[g];
        int q = q0 + g * 64 + w * 16 + ln;
        u16* cp = ctx + (b * 2048 + q) * 1024 + h * 64 + quad * 4;
#pragma unroll
        for (int nd = 0; nd < 4; ++nd) {
            u16x4 o = { f2b(oacc[g][nd][0] * linv), f2b(oacc[g][nd][1] * linv),
                        f2b(oacc[g][nd][2] * linv), f2b(oacc[g][nd][3] * linv) };
            *(u16x4*)(cp + nd * 16) = o;
        }
    }
}

// ---------------- launch ----------------
extern "C" void kernel_launch(void* const* d_in, const int* in_sizes, int n_in,
                              void* d_out, int out_size, void* d_ws, size_t ws_size,
                              hipStream_t stream) {
    const float* H   = (const float*)d_in[0];
    const float* wq  = (const float*)d_in[1];
    const float* wk  = (const float*)d_in[2];
    const float* wv  = (const float*)d_in[3];
    const float* wo  = (const float*)d_in[4];
    const float* rel = (const float*)d_in[5];
    float* out = (float*)d_out;

    char* ws = (char*)d_ws;
    u16* Hb    = (u16*)(ws);                 // 16.78 MB; reused as ctx after gemm
    u16* Wt    = (u16*)(ws + 16777216);      // 6.29 MB (wq|wk|wv transposed)
    u16* Wot   = (u16*)(ws + 23068672);      // 2.10 MB
    u16* Qb    = (u16*)(ws + 25165824);      // 16.78 MB
    u16* Kb    = (u16*)(ws + 41943040);      // 16.78 MB
    u16* Vt    = (u16*)(ws + 58720256);      // 16.78 MB, [bh][d][s]
    float* bias_tab = (float*)(ws + 75497472); // 0.26 MB
    u16* ctx = Hb;

    prep_kernel<<<5376, 256, 0, stream>>>(H, wq, wk, wv, wo, rel, Hb, Wt, Wot, bias_tab);
    gemm_bt<0><<<1536, 256, 0, stream>>>(Hb, Wt, 1024, 3072, Qb, Kb, Vt, nullptr);
    attn_kernel<<<512, 256, 0, stream>>>(Qb, Kb, Vt, bias_tab, ctx);
    gemm_bt<1><<<512, 256, 0, stream>>>(ctx, Wot, 1024, 1024, nullptr, nullptr, nullptr, out);
}